// Round 2
// 390.961 us; speedup vs baseline: 1.0129x; 1.0129x over previous
//
#include <hip/hip_runtime.h>
#include <hip/hip_bf16.h>

// KVEmbedding: out[b,l,:] = table[indices[b,l], :]
// indices: (4096, 200) int32  -> 819,200 rows
// table:   (1,000,000, 64) f32 (256 MB -- nearly fits the 256 MiB L3)
// out:     (4096, 200, 64) f32 (210 MB)
//
// Memory-bound gather. Thread t handles float4 #(t&15) of row (t>>4):
// 256B coalesced table reads, fully coalesced output stores.
//
// KEY CHANGE: output stores are NON-TEMPORAL (global_store_dwordx4 nt).
// The 210 MB write stream was allocating in L2/L3 and evicting the
// table, forcing ~143 MB of HBM table re-fetch every pass. With nt
// stores the table stays L3-resident (244 MiB vs 256 MiB L3), so
// steady-state reads come from Infinity Cache instead of HBM.
//
// NOTE: __builtin_nontemporal_store requires a NATIVE vector type --
// HIP's float4 (HIP_vector_type class) is rejected. Use ext_vector_type.

typedef float f32x4 __attribute__((ext_vector_type(4)));

__global__ __launch_bounds__(256) void KVEmbedding_56822417326208_kernel(
    const int* __restrict__ idx,
    const float* __restrict__ table,
    float* __restrict__ out,
    int n_rows) {
    long tid = (long)blockIdx.x * 256 + threadIdx.x;
    long total = (long)n_rows * 16;  // 16 float4 per 64-float row
    if (tid >= total) return;

    long row = tid >> 4;          // which (b,l) pair
    int  c   = (int)(tid & 15);   // which 16B chunk within the row

    long t = (long)idx[row];      // table row index (cached read, broadcast)
    const f32x4* __restrict__ src = (const f32x4*)(table + t * 64);
    f32x4 v = src[c];             // cached: we WANT table rows resident in L2/L3

    f32x4* __restrict__ dst = (f32x4*)(out + row * 64);
    __builtin_nontemporal_store(v, dst + c);  // nt: don't evict table from L3
}

extern "C" void kernel_launch(void* const* d_in, const int* in_sizes, int n_in,
                              void* d_out, int out_size, void* d_ws, size_t ws_size,
                              hipStream_t stream) {
    const int*   idx   = (const int*)d_in[0];
    const float* table = (const float*)d_in[1];
    // d_in[2] is the dummy scalar; its contribution is exactly 0.
    float* out = (float*)d_out;

    int n_rows = in_sizes[0];             // 4096*200 = 819,200
    long total = (long)n_rows * 16;       // one float4 per thread
    int  block = 256;
    long grid  = (total + block - 1) / block;

    KVEmbedding_56822417326208_kernel<<<dim3((unsigned)grid), dim3(block), 0, stream>>>(
        idx, table, out, n_rows);
}